// Round 11
// baseline (204.874 us; speedup 1.0000x reference)
//
#include <hip/hip_runtime.h>
#include <math.h>

// ToyModel: B=4, S=2048, E=256, H=512, VOCAB=50257.
// Inputs/output f32; intermediates bf16; MFMA bf16 w/ f32 accum. posneg == identity.
//
// Round 11: occupancy experiment — all GEMMs to BN=128 tiles with tight
// __launch_bounds__ (QK 128x128 @ (256,3) ~3 blk/CU; PV 64x128 splitK @ (256,4);
// QKV 64x128 @ (256,4), 1536 blocks). Hypothesis: the limiter is the per-iter
// barrier vmcnt drain at 2 blk/CU, not MFMA density; more resident waves hide it.
//
// ws: q@0 | k@8MiB | vT@16MiB | sc@24MiB(32MiB) | lsum@56MiB(1MB, 32 partials).
// embB aliases sc (dead before sc written); wsP aliases q+k (dead by PV).

typedef unsigned short u16;
typedef u16   u16x8 __attribute__((ext_vector_type(8)));
typedef short s16x8 __attribute__((ext_vector_type(8)));
typedef float f32x4 __attribute__((ext_vector_type(4)));
typedef float f32x8 __attribute__((ext_vector_type(8)));

static __device__ __forceinline__ u16 f2bf(float f) {
    unsigned u = __builtin_bit_cast(unsigned, f);
    u = (u + 0x7fffu + ((u >> 16) & 1u)) >> 16;   // RNE
    return (u16)u;
}

static __device__ __forceinline__ void gload_lds16(const u16* g, u16* l) {
    __builtin_amdgcn_global_load_lds(
        (const __attribute__((address_space(1))) void*)g,
        (__attribute__((address_space(3))) void*)l, 16, 0, 0);
}

struct PArgs {
    const float* wsrc[4];
    u16*         wdst[4];
    int          wK[4];
    const float* emb;
    const int*   tok;
    u16*         embB;
};

// z<4: f32 W[K][512] -> bf16 WT[512][K]. z>=4: XCD-striped gather+cvt of emb rows.
__launch_bounds__(256)
__global__ void prep_k(PArgs p)
{
    const int z = blockIdx.z;
    if (z < 4) {
        const float* W = p.wsrc[z];
        u16* WT = p.wdst[z];
        const int K = p.wK[z];
        const int c0 = blockIdx.x * 64;
        const int r0 = blockIdx.y * 64;
        if (r0 >= K) return;
        __shared__ float T[64][65];
        const int t = threadIdx.x;
        const int col = t & 63;
        const int rb  = t >> 6;
#pragma unroll
        for (int i = 0; i < 16; ++i)
            T[i * 4 + rb][col] = W[(long)(r0 + i * 4 + rb) * 512 + c0 + col];
        __syncthreads();
#pragma unroll
        for (int i = 0; i < 16; ++i) {
            const int orow = i * 4 + rb;
            WT[(long)(c0 + orow) * K + r0 + col] = f2bf(T[col][orow]);
        }
    } else {
        const int b = (z - 4) * 64 + blockIdx.y * 8 + blockIdx.x;   // 0..1023
        const int g = (b & 7) * 128 + (b >> 3);
        const int t = g * 2048 + threadIdx.x * 8;
        const int row = t >> 8;
        const int c8  = t & 255;
        f32x8 v = *(const f32x8*)(p.emb + (long)p.tok[row] * 256 + c8);
        u16x8 o;
#pragma unroll
        for (int j = 0; j < 8; ++j) o[j] = f2bf(v[j]);
        *(u16x8*)(p.embB + (long)row * 256 + c8) = o;
    }
}

struct GArgs {
    const u16* A; const u16* B; const float* bias; void* C;
    float* Cpart;
    float* lsum;                          // [32][8192] QK row partial sums
    u16 *qd, *kd, *vTd;
    const float *bq, *bk, *bv;
    int K, lda, ldb, ldc;
    long strA, strB, strC;
    float scale;
};

// MFMA GEMM, dbuf async staging. BM=TM*32, BN=NT*32, BK=32. 4 waves 2x2.
// EPI: 0 scale, 1 +bias, 2 +bias+GELU.
// CMODE: 0 bf16 C, 1 f32 C, 2 QKV-fused (n0<1024: q/k row-major; n0>=1024:
//        v repacked via LDS -> vT[batch][h][pos]), 3 QK+exp (+lsum partials).
// MX: m-tile fastest. SPLITK: z=batch*2+kh, K half = 1024. XSW: XCD m-stripes.
// MINW: min waves/EU for __launch_bounds__ (VGPR cap / occupancy target).
template <int TM, int NT, int EPI, int CMODE, bool MX, bool SPLITK, bool XSW, int MINW>
__launch_bounds__(256, MINW)
__global__ void gemm128(GArgs g)
{
    constexpr int BM  = TM * 32;
    constexpr int BN  = NT * 32;
    constexpr int ASZ = BM * 32;
    constexpr int BSZ = BN * 32;
    __shared__ u16 smem[2 * (ASZ + BSZ)];
    u16* As = smem;
    u16* Bs = smem + 2 * ASZ;

    const int bz    = blockIdx.z;
    const int batch = SPLITK ? (bz >> 1) : bz;
    const int kh    = SPLITK ? (bz & 1) : 0;
    const u16* A = g.A + g.strA * batch + (SPLITK ? kh * 1024 : 0);
    const u16* B = g.B + g.strB * batch + (SPLITK ? kh * 1024 : 0);

    int m0, n0;
    if (XSW) {
        const int lid = blockIdx.y * gridDim.x + blockIdx.x;
        const int xcd = lid & 7;
        const int j   = lid >> 3;
        const int mper = gridDim.y >> 3;
        m0 = (xcd * mper + (j % mper)) * BM;
        n0 = (j / mper) * BN;
    } else {
        m0 = (MX ? blockIdx.x : blockIdx.y) * BM;
        n0 = (MX ? blockIdx.y : blockIdx.x) * BN;
    }

    const int t = threadIdx.x;
    const int w = t >> 6;
    const int lane = t & 63;
    const int quad = lane >> 4;
    const int l16  = lane & 15;
    const int wm = w >> 1, wn = w & 1;

    const int srow = w * 16 + (lane >> 2);
    const int skc  = (lane & 3) * 8;
    const u16* ga = A + (long)(m0 + srow) * g.lda + skc;
    const u16* gb = B + (long)(n0 + srow) * g.ldb + skc;
    const long a64 = (long)64 * g.lda;
    const long b64 = (long)64 * g.ldb;
    u16* lA = As + w * 512;
    u16* lB = Bs + w * 512;

    auto stage = [&](int buf, int k0) {
        u16* la = lA + buf * ASZ;
        u16* lb = lB + buf * BSZ;
#pragma unroll
        for (int i = 0; i < TM / 2; ++i) gload_lds16(ga + i * a64 + k0, la + i * 2048);
#pragma unroll
        for (int i = 0; i < NT / 2; ++i) gload_lds16(gb + i * b64 + k0, lb + i * 2048);
    };

    f32x4 acc[TM][NT] = {};
    const int K = SPLITK ? 1024 : g.K;

    stage(0, 0);
    int cur = 0;
    for (int k0 = 0; k0 < K; k0 += 32) {
        __syncthreads();
        if (k0 + 32 < K) stage(cur ^ 1, k0 + 32);

        const u16* as = As + cur * ASZ;
        const u16* bs = Bs + cur * BSZ;
        s16x8 af[TM], bf[NT];
#pragma unroll
        for (int x = 0; x < TM; ++x)
            af[x] = *(const s16x8*)&as[(wm * (TM * 16) + x * 16 + l16) * 32 + quad * 8];
#pragma unroll
        for (int y = 0; y < NT; ++y)
            bf[y] = *(const s16x8*)&bs[(wn * (NT * 16) + y * 16 + l16) * 32 + quad * 8];
#pragma unroll
        for (int x = 0; x < TM; ++x)
#pragma unroll
            for (int y = 0; y < NT; ++y)
                acc[x][y] = __builtin_amdgcn_mfma_f32_16x16x32_bf16(af[x], bf[y], acc[x][y], 0, 0, 0);
        cur ^= 1;
    }

    // ---- v-block epilogue (QKV fused, n0 >= 1024): LDS repack -> vT ----
    if (CMODE == 2 && n0 >= 1024) {
        u16* T = smem;                    // [BN][72] u16 = 18432 B <= smem 24576 B
        __syncthreads();                  // all waves done reading As/Bs
#pragma unroll
        for (int y = 0; y < NT; ++y) {
            const int crel = wn * (NT * 16) + y * 16 + l16;
            const float bval = g.bv[n0 - 1024 + crel];
#pragma unroll
            for (int x = 0; x < TM; ++x)
#pragma unroll
                for (int r = 0; r < 4; ++r) {
                    const int rrel = wm * (TM * 16) + x * 16 + quad * 4 + r;
                    T[crel * 72 + rrel] = f2bf(acc[x][y][r] + bval);
                }
        }
        __syncthreads();
        const int vb  = m0 >> 11;         // batch (BM=64 divides 2048)
        const int pos = m0 & 2047;
        u16* dst = g.vTd + (long)vb * (512l * 2048) + (long)(n0 - 1024) * 2048 + pos;
#pragma unroll
        for (int i = 0; i < BN / 32; ++i) {
            const int c  = i * 32 + (t >> 3);
            const int ms = (t & 7) * 8;
            *(u16x8*)(dst + (long)c * 2048 + ms) = *(const u16x8*)&T[c * 72 + ms];
        }
        return;
    }

    float rs[TM][4];
    if (CMODE == 3)
#pragma unroll
        for (int x = 0; x < TM; ++x)
#pragma unroll
            for (int r = 0; r < 4; ++r) rs[x][r] = 0.0f;

#pragma unroll
    for (int y = 0; y < NT; ++y) {
        const int col = n0 + wn * (NT * 16) + y * 16 + l16;
        float bval = 0.0f;
        if (CMODE == 2)
            bval = col < 512 ? g.bq[col] : g.bk[col - 512];
        else if (EPI >= 1)
            bval = g.bias[col];
#pragma unroll
        for (int x = 0; x < TM; ++x) {
#pragma unroll
            for (int r = 0; r < 4; ++r) {
                const int row = m0 + wm * (TM * 16) + x * 16 + quad * 4 + r;
                float v = acc[x][y][r] * g.scale + bval;
                if (EPI == 2) v = 0.5f * v * (1.0f + erff(v * 0.70710678118654752f));
                if (CMODE == 3) {
                    const float e = __expf(v);
                    rs[x][r] += e;
                    ((u16*)g.C + g.strC * batch)[(long)row * g.ldc + col] = f2bf(e);
                } else if (CMODE == 2) {
                    u16* dst = col < 512 ? g.qd : g.kd;
                    dst[(long)row * 512 + (col & 511)] = f2bf(v);
                } else if (SPLITK) {
                    float* dst = kh ? g.Cpart : (float*)g.C;
                    dst[g.strC * batch + (long)row * g.ldc + col] = v;
                } else if (CMODE == 1) {
                    ((float*)g.C + g.strC * batch)[(long)row * g.ldc + col] = v;
                } else {
                    ((u16*)g.C + g.strC * batch)[(long)row * g.ldc + col] = f2bf(v);
                }
            }
        }
    }

    if (CMODE == 3) {
        // per-row sums over this block's 128 cols: reduce 16 l16 lanes, store
        // one partial per (n-block, wave-half): slot = 2*blockIdx.x + wn (0..31).
#pragma unroll
        for (int x = 0; x < TM; ++x) {
#pragma unroll
            for (int r = 0; r < 4; ++r) {
                float s = rs[x][r];
                s += __shfl_xor(s, 1, 64);
                s += __shfl_xor(s, 2, 64);
                s += __shfl_xor(s, 4, 64);
                s += __shfl_xor(s, 8, 64);
                if (l16 == 0) {
                    const int row = m0 + wm * (TM * 16) + x * 16 + quad * 4 + r;
                    g.lsum[(long)(2 * blockIdx.x + wn) * 8192 + batch * 2048 + row] = s;
                }
            }
        }
    }
}

// out[i] = (out[i] + part[i]) / l[row].  4 f32 per thread, 4096 blocks.
__launch_bounds__(256)
__global__ void add_k(float* __restrict__ out, const float* __restrict__ part,
                      const float* __restrict__ lsum)
{
    const long i = ((long)blockIdx.x * 256 + threadIdx.x) * 4;
    const int row = (int)(i >> 9);                 // 512 f32 per row
    float l = 0.0f;
#pragma unroll
    for (int j = 0; j < 32; ++j) l += lsum[(long)j * 8192 + row];
    const float inv = 1.0f / l;
    f32x4 a = *(const f32x4*)(out + i);
    f32x4 b = *(const f32x4*)(part + i);
    a = (a + b) * inv;
    *(f32x4*)(out + i) = a;
}

extern "C" void kernel_launch(void* const* d_in, const int* in_sizes, int n_in,
                              void* d_out, int out_size, void* d_ws, size_t ws_size,
                              hipStream_t stream)
{
    const int*   tok = (const int*)d_in[0];
    const float* emb = (const float*)d_in[1];
    const float* W1  = (const float*)d_in[2];
    const float* b1  = (const float*)d_in[3];
    const float* Wq  = (const float*)d_in[4];
    const float* bq  = (const float*)d_in[5];
    const float* Wk  = (const float*)d_in[6];
    const float* bk  = (const float*)d_in[7];
    const float* Wv  = (const float*)d_in[8];
    const float* bv  = (const float*)d_in[9];
    float* out = (float*)d_out;

    u16* act   = (u16*)d_out;                  // [8192][512] bf16 (8 MiB)
    u16* wbase = act + 8192l * 512;
    u16* W1T = wbase;                          // [512][256]
    u16* WqT = wbase + 131072;                 // [1536][512] contiguous
    u16* WkT = WqT + 262144;
    u16* WvT = WkT + 262144;

    char* ws = (char*)d_ws;
    u16* q     = (u16*)(ws);
    u16* k     = (u16*)(ws + (8l  << 20));
    u16* vT    = (u16*)(ws + (16l << 20));     // [4][512][2048]
    u16* sc    = (u16*)(ws + (24l << 20));     // 32 MiB (e values)
    float* lsum = (float*)(ws + (56l << 20));  // [32][8192] f32
    u16* embB  = sc;                           // dead before sc written
    float* wsP = (float*)ws;                   // aliases q+k (dead by PV)

    const dim3 blk(256);
    const float iscl = 0.044194173824159216f;  // 1/sqrt(512)
    const long  TB = 2048l * 512;
    const long  SS = 2048l * 2048;

    // 0. prep: weight transposes (z<4) + XCD-striped gather+cvt (z>=4)
    PArgs p;
    p.wsrc[0] = W1; p.wsrc[1] = Wq; p.wsrc[2] = Wk; p.wsrc[3] = Wv;
    p.wdst[0] = W1T; p.wdst[1] = WqT; p.wdst[2] = WkT; p.wdst[3] = WvT;
    p.wK[0] = 256; p.wK[1] = 512; p.wK[2] = 512; p.wK[3] = 512;
    p.emb = emb; p.tok = tok; p.embB = embB;
    prep_k<<<dim3(8, 8, 20), blk, 0, stream>>>(p);

    // 1. act = gelu(embB @ W1T + b1)   M=8192 N=512 K=256  TM=2/NT=4 XSW (512 blocks)
    {
        GArgs a = {};
        a.A = embB; a.B = W1T; a.bias = b1; a.C = act;
        a.K = 256; a.lda = 256; a.ldb = 256; a.ldc = 512; a.scale = 1.0f;
        gemm128<2, 4, 2, 0, false, false, true, 4><<<dim3(4, 128, 1), blk, 0, stream>>>(a);
    }
    // 2. fused QKV   M=8192 N=1536 K=512  TM=2/NT=4 XSW (1536 blocks, ~6 blk/CU)
    {
        GArgs a = {};
        a.A = act; a.B = WqT; a.K = 512; a.lda = 512; a.ldb = 512; a.scale = 1.0f;
        a.qd = q; a.kd = k; a.vTd = vT; a.bq = bq; a.bk = bk; a.bv = bv;
        gemm128<2, 4, 0, 2, false, false, true, 4><<<dim3(12, 128, 1), blk, 0, stream>>>(a);
    }
    // 3. e = exp(q @ k^T / sqrt(512)) + row sums   M=N=2048 K=512
    //    TM=4/NT=4 (128x128, 1024 blocks, ~3 blk/CU target)
    {
        GArgs a = {};
        a.A = q; a.B = k; a.C = sc; a.lsum = lsum;
        a.K = 512; a.lda = 512; a.ldb = 512; a.ldc = 2048;
        a.strA = TB; a.strB = TB; a.strC = SS; a.scale = iscl;
        gemm128<4, 4, 0, 3, false, false, false, 3><<<dim3(16, 16, 4), blk, 0, stream>>>(a);
    }
    // 4. raw = e @ vT^T   M=2048 N=512 K=2048  TM=2/NT=4, split-K x2, MX (1024 blocks)
    {
        GArgs a = {};
        a.A = sc; a.B = vT; a.C = out; a.Cpart = wsP;
        a.K = 2048; a.lda = 2048; a.ldb = 2048; a.ldc = 512;
        a.strA = SS; a.strB = TB; a.strC = TB; a.scale = 1.0f;
        gemm128<2, 4, 0, 1, true, true, false, 4><<<dim3(32, 4, 8), blk, 0, stream>>>(a);
    }
    // 5. out = (kh0 + kh1) / l_row
    add_k<<<dim3(4096), blk, 0, stream>>>(out, wsP, lsum);
}